// Round 7
// baseline (238.185 us; speedup 1.0000x reference)
//
#include <hip/hip_runtime.h>
#include <math.h>

#define B_ 64
#define P_ 24564
#define G_ 48

// Workspace layout (total ~3.18 MB):
//   [0]     unsigned long long bpk[B_*G_]   (memset 0 each call; atomicMax targets)
//   [24576] unsigned int done               (memset 0 each call; block-done counter)
//   [24832] float        pl[NBLK]           per-block loss partials (overwritten)
//   [30976] unsigned int pn[NBLK]           per-block npos partials (overwritten)
//   [37120] unsigned short mrec[B_*PAD_P]   i1|i2<<6|pos<<12 (overwritten)
constexpr int CH    = 1024;
constexpr int NCH   = 24;               // 24*1024 = 24576 >= P_
constexpr int PAD_P = NCH * CH;
constexpr int PPT   = 4;
constexpr int NBLK  = NCH * B_;         // 1536
constexpr int ROW   = 132;              // kgrid row in u32 (128 entries + pad)

__device__ __forceinline__ float frcp(float x) { return __builtin_amdgcn_rcpf(x); }

// Smooth-ln repulsion term; identical in match (default) and fixup (correction) so terms cancel.
__device__ __forceinline__ float loss_term(float4 pr, float4 l, float4 gb, float ga) {
    float cx = pr.x + l.x * 0.1f * pr.z;
    float cy = pr.y + l.y * 0.1f * pr.w;
    float w  = pr.z * expf(l.z * 0.2f);
    float h  = pr.w * expf(l.w * 0.2f);
    float dx1 = cx - w * 0.5f, dy1 = cy - h * 0.5f;
    float dx2 = cx + w * 0.5f, dy2 = cy + h * 0.5f;
    float ix1 = fmaxf(gb.x, dx1), iy1 = fmaxf(gb.y, dy1);
    float ix2 = fminf(gb.z, dx2), iy2 = fminf(gb.w, dy2);
    float iw = fmaxf(ix2 - ix1, 0.0f), ih = fmaxf(iy2 - iy1, 0.0f);
    float iogv = (iw * ih) * frcp(ga + 1e-7f);
    float r = 0.0f;
    if (iogv < 0.95f) {
        if (iogv < 0.5f)
            r = -logf(1.0f - iogv + 1e-7f);
        else
            r = (iogv - 0.5f) * 2.0f + 0.69314718055994531f;  // -ln(0.5)
    }
    return r;
}

// ---------------- mega: match everywhere; LAST block also does fix + final ------------------
__global__ __launch_bounds__(256) void mega_kernel(
    const float* __restrict__ pred_loc, const float* __restrict__ priors,
    const float* __restrict__ gt, unsigned long long* __restrict__ bpk,
    unsigned int* __restrict__ done, unsigned short* __restrict__ mrec,
    float* __restrict__ pl, unsigned int* __restrict__ pn, float* __restrict__ out) {
    const int b    = blockIdx.y;
    const int base = blockIdx.x * CH;
    const int tid  = threadIdx.x;

    __shared__ float4 sbox[G_];
    __shared__ float  sga[G_];
    __shared__ unsigned int kgrid[G_ * ROW];   // match: candidate keys | fixup: sp[] alias
    __shared__ unsigned int pmax[G_][4];
    __shared__ float rs[4];
    __shared__ unsigned int rn[4];
    __shared__ unsigned int s_last;

    if (tid < G_) {
        const float* q = gt + ((size_t)b * G_ + tid) * 5;
        float x1 = q[0], y1 = q[1], x2 = q[2], y2 = q[3];
        sbox[tid] = make_float4(x1, y1, x2, y2);
        sga[tid]  = (x2 - x1) * (y2 - y1);
    }
    __syncthreads();

    float px1[PPT], py1[PPT], px2[PPT], py2[PPT], pa[PPT];
    unsigned int tb[PPT];  // 1023 - local_p (per-gt tie-break: lower p wins)
#pragma unroll
    for (int j = 0; j < PPT; j++) {
        int lp = tid + 256 * j;
        int pc = min(base + lp, P_ - 1);  // clamped OOB dup loses tie-break to the real one
        float4 pr = ((const float4*)priors)[pc];
        float hx = pr.z * 0.5f, hy = pr.w * 0.5f;
        px1[j] = pr.x - hx; py1[j] = pr.y - hy;
        px2[j] = pr.x + hx; py2[j] = pr.y + hy;
        pa[j] = (px2[j] - px1[j]) * (py2[j] - py1[j]);
        tb[j] = (unsigned)(1023 - lp);
    }

    unsigned int k1[PPT], k2[PPT];  // packed top-2 of r=inter/(ga+pa): (r&~0x3F)|(63-g)
#pragma unroll
    for (int j = 0; j < PPT; j++) { k1[j] = 0u; k2[j] = 0u; }

#pragma unroll 8
    for (int g = 0; g < G_; g++) {
        float4 gb = sbox[g];
        float  ga = sga[g];
        unsigned int gmax = 0u;
#pragma unroll
        for (int j = 0; j < PPT; j++) {
            float ix1 = fmaxf(gb.x, px1[j]), iy1 = fmaxf(gb.y, py1[j]);
            float ix2 = fminf(gb.z, px2[j]), iy2 = fminf(gb.w, py2[j]);
            float iw = fmaxf(ix2 - ix1, 0.0f), ih = fmaxf(iy2 - iy1, 0.0f);
            float inter = iw * ih;
            // r = inter/(ga+pa) is a monotone transform of IoU=inter/(ga+pa-inter)
            float r = inter * frcp(ga + pa[j]);
            unsigned int vb = __float_as_uint(r);
            unsigned int pk = (vb & 0xFFFFFFC0u) | (unsigned)(63 - g);
            k2[j] = max(k2[j], min(k1[j], pk));
            k1[j] = max(k1[j], pk);
            unsigned int gk = (vb & 0xFFFFFC00u) | tb[j];
            gmax = max(gmax, gk);
        }
        // pair-reduce across adjacent lanes, even lanes store -> 128-entry rows
        unsigned int o = __shfl_down(gmax, 1, 64);
        if ((tid & 1) == 0) kgrid[g * ROW + (tid >> 1)] = max(gmax, o);
    }

    // per-prior epilogue: default contribution assumes NO override (bi=i1 -> rep=i2)
    float contrib = 0.0f;
    unsigned int np = 0;
#pragma unroll
    for (int j = 0; j < PPT; j++) {
        int p = base + tid + 256 * j;
        unsigned int i1 = 63u - (k1[j] & 63u);
        unsigned int i2 = 63u - (k2[j] & 63u);
        // r >= 1/3  <=>  IoU >= 0.5 ; truncated-key threshold (bits(1/3f) & ~0x3F)
        unsigned int pos = (k1[j] >= 0x3EAAAA80u) ? 1u : 0u;
        mrec[(size_t)b * PAD_P + base + tid + 256 * j] =
            (unsigned short)(i1 | (i2 << 6) | (pos << 12));
        if (p < P_ && pos) {
            float4 pr = ((const float4*)priors)[p];               // L1-hot reload
            float4 l  = ((const float4*)pred_loc)[(size_t)b * P_ + p];
            contrib += loss_term(pr, l, sbox[i2], sga[i2]);
            np++;
        }
    }

    const int lane = tid & 63, wv = tid >> 6;
    for (int off = 32; off; off >>= 1) {
        contrib += __shfl_down(contrib, off, 64);
        np      += __shfl_down(np, off, 64);
    }
    if (lane == 0) { rs[wv] = contrib; rn[wv] = np; }
    __syncthreads();  // kgrid + rs/rn visible

    // per-gt argmax within block: 4 readers per gt scan 32 entries each
    if (tid < 192) {
        int g = tid >> 2, qq = tid & 3;
        const uint4* row = (const uint4*)&kgrid[g * ROW + qq * 32];
        unsigned int m = 0u;
#pragma unroll
        for (int i = 0; i < 8; i++) {
            uint4 v = row[i];
            m = max(max(m, v.x), max(v.y, max(v.z, v.w)));
        }
        pmax[g][qq] = m;
    }
    __syncthreads();

    if (tid < G_) {
        unsigned int w = max(max(pmax[tid][0], pmax[tid][1]),
                             max(pmax[tid][2], pmax[tid][3]));
        int p = base + 1023 - (int)(w & 0x3FFu);
        p = min(p, P_ - 1);  // defensive; unreachable via tie-break
        float4 pr = ((const float4*)priors)[p];
        float hx = pr.z * 0.5f, hy = pr.w * 0.5f;
        float qx1 = pr.x - hx, qy1 = pr.y - hy, qx2 = pr.x + hx, qy2 = pr.y + hy;
        float pae = (qx2 - qx1) * (qy2 - qy1);
        float4 gb = sbox[tid];
        float ix1 = fmaxf(gb.x, qx1), iy1 = fmaxf(gb.y, qy1);
        float ix2 = fminf(gb.z, qx2), iy2 = fminf(gb.w, qy2);
        float iw = fmaxf(ix2 - ix1, 0.0f), ih = fmaxf(iy2 - iy1, 0.0f);
        float inter = iw * ih;
        // exact (bit-stable across blocks) IoU-form key for cross-block comparison
        float v = inter * frcp(sga[tid] + pae - inter);
        unsigned long long key = ((unsigned long long)__float_as_uint(v) << 32) |
                                 (unsigned long long)(0xFFFFFFFFu - (unsigned)p);
        atomicMax(&bpk[(size_t)b * G_ + tid], key);
    }

    if (tid == 0) {
        pl[b * NCH + blockIdx.x] = rs[0] + rs[1] + rs[2] + rs[3];
        pn[b * NCH + blockIdx.x] = rn[0] + rn[1] + rn[2] + rn[3];
    }

    // ---- signal done; last block performs fix + final ----
    __threadfence();          // make this thread's global stores device-visible
    __syncthreads();          // all threads' fences executed
    if (tid == 0) {
        unsigned int t = atomicAdd(done, 1u);
        s_last = (t == (unsigned)(NBLK - 1)) ? 1u : 0u;
    }
    __syncthreads();
    if (!s_last) return;
    __threadfence();          // acquire: other blocks' stores now visible

    // ---------------- fixup phase (one block, 256 threads) ----------------
    int* sp = (int*)kgrid;    // alias: 3072 ints = 12 KB (kgrid is 25 KB)
    for (int i = tid; i < B_ * G_; i += 256) {
        unsigned long long k = bpk[i];
        sp[i] = (int)(0xFFFFFFFFu - (unsigned)(k & 0xFFFFFFFFull));
    }
    __syncthreads();

    float dl = 0.0f;
    unsigned int dn = 0;
    for (int i = tid; i < B_ * G_; i += 256) {
        int bb = i / G_, g = i - bb * G_;
        int p = sp[i];
        // last-write-wins: g is alive iff no larger g' in the same image shares p
        bool alive = true;
        for (int d = g + 1; d < G_; d++)
            if (sp[bb * G_ + d] == p) alive = false;
        if (alive) {
            unsigned int m = mrec[(size_t)bb * PAD_P + p];
            int i1 = (int)(m & 63u), i2 = (int)((m >> 6) & 63u);
            bool pos0 = (m >> 12) & 1u;
            int ri = (g == i1) ? i2 : i1;   // override bi=g -> rep flips to i1 unless g==i1
            float4 pr = ((const float4*)priors)[p];
            float4 l  = ((const float4*)pred_loc)[(size_t)bb * P_ + p];
            const float* qr = gt + ((size_t)bb * G_ + ri) * 5;
            float4 gbr = make_float4(qr[0], qr[1], qr[2], qr[3]);
            float gar = (qr[2] - qr[0]) * (qr[3] - qr[1]);
            float cnew = loss_term(pr, l, gbr, gar);
            float cold = 0.0f;
            if (pos0) {
                const float* q2 = gt + ((size_t)bb * G_ + i2) * 5;
                float4 gb2 = make_float4(q2[0], q2[1], q2[2], q2[3]);
                float ga2 = (q2[2] - q2[0]) * (q2[3] - q2[1]);
                cold = loss_term(pr, l, gb2, ga2);   // cancels match's default term
            } else {
                dn++;                                 // prior newly positive
            }
            dl += cnew - cold;
        }
    }

    // fold in per-block partials
    for (int i = tid; i < NBLK; i += 256) { dl += pl[i]; dn += pn[i]; }

    for (int off = 32; off; off >>= 1) {
        dl += __shfl_down(dl, off, 64);
        dn += __shfl_down(dn, off, 64);
    }
    if (lane == 0) { rs[wv] = dl; rn[wv] = dn; }
    __syncthreads();
    if (tid == 0) {
        double s = (double)rs[0] + (double)rs[1] + (double)rs[2] + (double)rs[3];
        unsigned int n = rn[0] + rn[1] + rn[2] + rn[3];
        out[0] = (float)(s / (double)n);
    }
}

extern "C" void kernel_launch(void* const* d_in, const int* in_sizes, int n_in,
                              void* d_out, int out_size, void* d_ws, size_t ws_size,
                              hipStream_t stream) {
    const float* pred_loc = (const float*)d_in[0];  // [B,P,4]
    const float* priors   = (const float*)d_in[1];  // [P,4]
    const float* gt       = (const float*)d_in[2];  // [B,G,5]
    float* out = (float*)d_out;

    char* ws = (char*)d_ws;
    unsigned long long* bpk = (unsigned long long*)ws;                    // 24576 B
    unsigned int* done = (unsigned int*)(ws + 24576);                     // 4 B
    float*        pl   = (float*)(ws + 24832);                            // 6144 B
    unsigned int* pn   = (unsigned int*)(ws + 30976);                     // 6144 B
    unsigned short* mrec = (unsigned short*)(ws + 37120);                 // 3145728 B

    hipMemsetAsync(ws, 0, 24832, stream);   // bpk + done

    dim3 g1(NCH, B_);
    mega_kernel<<<g1, 256, 0, stream>>>(pred_loc, priors, gt, bpk, done, mrec, pl, pn, out);
}

// Round 8
// 143.558 us; speedup vs baseline: 1.6592x; 1.6592x over previous
//
#include <hip/hip_runtime.h>
#include <math.h>

#define B_ 64
#define P_ 24564
#define G_ 48

// Workspace layout (total ~3.75 MB), everything fully overwritten every call (no memset):
//   [0]        unsigned long long bkey[B_][G_][NCH]   per-(b,g,chunk) best-prior keys
//   [589824]   unsigned short mrec[B_*PAD_P]          i1|i2<<6|pos<<12
//   [3735552]  float        pl[NBLK]                  per-block loss partials
//   [3741696]  unsigned int pn[NBLK]                  per-block npos partials
constexpr int CH    = 1024;
constexpr int NCH   = 24;               // 24*1024 = 24576 >= P_
constexpr int PAD_P = NCH * CH;
constexpr int PPT   = 4;
constexpr int NBLK  = NCH * B_;         // 1536
constexpr int ROW   = 132;              // kgrid row in u32 (128 entries + pad)

__device__ __forceinline__ float frcp(float x) { return __builtin_amdgcn_rcpf(x); }

// Smooth-ln repulsion term; identical in match (default) and fixup (correction) so terms cancel.
__device__ __forceinline__ float loss_term(float4 pr, float4 l, float4 gb, float ga) {
    float cx = pr.x + l.x * 0.1f * pr.z;
    float cy = pr.y + l.y * 0.1f * pr.w;
    float w  = pr.z * expf(l.z * 0.2f);
    float h  = pr.w * expf(l.w * 0.2f);
    float dx1 = cx - w * 0.5f, dy1 = cy - h * 0.5f;
    float dx2 = cx + w * 0.5f, dy2 = cy + h * 0.5f;
    float ix1 = fmaxf(gb.x, dx1), iy1 = fmaxf(gb.y, dy1);
    float ix2 = fminf(gb.z, dx2), iy2 = fminf(gb.w, dy2);
    float iw = fmaxf(ix2 - ix1, 0.0f), ih = fmaxf(iy2 - iy1, 0.0f);
    float iogv = (iw * ih) * frcp(ga + 1e-7f);
    float r = 0.0f;
    if (iogv < 0.95f) {
        if (iogv < 0.5f)
            r = -logf(1.0f - iogv + 1e-7f);
        else
            r = (iogv - 0.5f) * 2.0f + 0.69314718055994531f;  // -ln(0.5)
    }
    return r;
}

// ---------------- K1: fused — top-2 per prior, per-gt block argmax, default loss ------------
__global__ __launch_bounds__(256) void match_kernel(
    const float* __restrict__ pred_loc, const float* __restrict__ priors,
    const float* __restrict__ gt, unsigned long long* __restrict__ bkey,
    unsigned short* __restrict__ mrec, float* __restrict__ pl, unsigned int* __restrict__ pn) {
    const int b    = blockIdx.y;
    const int base = blockIdx.x * CH;
    const int tid  = threadIdx.x;

    __shared__ float4 sbox[G_];
    __shared__ float  sga[G_];
    __shared__ unsigned int kgrid[G_ * ROW];   // pair-reduced per-gt candidate keys
    __shared__ unsigned int pmax[G_][4];
    __shared__ float rs[4];
    __shared__ unsigned int rn[4];

    if (tid < G_) {
        const float* q = gt + ((size_t)b * G_ + tid) * 5;
        float x1 = q[0], y1 = q[1], x2 = q[2], y2 = q[3];
        sbox[tid] = make_float4(x1, y1, x2, y2);
        sga[tid]  = (x2 - x1) * (y2 - y1);
    }
    __syncthreads();

    float px1[PPT], py1[PPT], px2[PPT], py2[PPT], pa[PPT];
    unsigned int tb[PPT];  // 1023 - local_p (per-gt tie-break: lower p wins)
#pragma unroll
    for (int j = 0; j < PPT; j++) {
        int lp = tid + 256 * j;
        int pc = min(base + lp, P_ - 1);  // clamped OOB dup loses tie-break to the real one
        float4 pr = ((const float4*)priors)[pc];
        float hx = pr.z * 0.5f, hy = pr.w * 0.5f;
        px1[j] = pr.x - hx; py1[j] = pr.y - hy;
        px2[j] = pr.x + hx; py2[j] = pr.y + hy;
        pa[j] = (px2[j] - px1[j]) * (py2[j] - py1[j]);
        tb[j] = (unsigned)(1023 - lp);
    }

    unsigned int k1[PPT], k2[PPT];  // packed top-2 of r=inter/(ga+pa): (r&~0x3F)|(63-g)
#pragma unroll
    for (int j = 0; j < PPT; j++) { k1[j] = 0u; k2[j] = 0u; }

#pragma unroll 8
    for (int g = 0; g < G_; g++) {
        float4 gb = sbox[g];
        float  ga = sga[g];
        unsigned int gmax = 0u;
#pragma unroll
        for (int j = 0; j < PPT; j++) {
            float ix1 = fmaxf(gb.x, px1[j]), iy1 = fmaxf(gb.y, py1[j]);
            float ix2 = fminf(gb.z, px2[j]), iy2 = fminf(gb.w, py2[j]);
            float iw = fmaxf(ix2 - ix1, 0.0f), ih = fmaxf(iy2 - iy1, 0.0f);
            float inter = iw * ih;
            // r = inter/(ga+pa) is a monotone transform of IoU=inter/(ga+pa-inter)
            float r = inter * frcp(ga + pa[j]);
            unsigned int vb = __float_as_uint(r);
            unsigned int pk = (vb & 0xFFFFFFC0u) | (unsigned)(63 - g);
            k2[j] = max(k2[j], min(k1[j], pk));
            k1[j] = max(k1[j], pk);
            unsigned int gk = (vb & 0xFFFFFC00u) | tb[j];
            gmax = max(gmax, gk);
        }
        // pair-reduce across adjacent lanes, even lanes store -> 128-entry rows
        unsigned int o = __shfl_down(gmax, 1, 64);
        if ((tid & 1) == 0) kgrid[g * ROW + (tid >> 1)] = max(gmax, o);
    }

    // per-prior epilogue: default contribution assumes NO override (bi=i1 -> rep=i2)
    float contrib = 0.0f;
    unsigned int np = 0;
#pragma unroll
    for (int j = 0; j < PPT; j++) {
        int p = base + tid + 256 * j;
        unsigned int i1 = 63u - (k1[j] & 63u);
        unsigned int i2 = 63u - (k2[j] & 63u);
        // r >= 1/3  <=>  IoU >= 0.5 ; truncated-key threshold (bits(1/3f) & ~0x3F)
        unsigned int pos = (k1[j] >= 0x3EAAAA80u) ? 1u : 0u;
        mrec[(size_t)b * PAD_P + base + tid + 256 * j] =
            (unsigned short)(i1 | (i2 << 6) | (pos << 12));
        if (p < P_ && pos) {
            float4 pr = ((const float4*)priors)[p];               // L1-hot reload
            float4 l  = ((const float4*)pred_loc)[(size_t)b * P_ + p];
            contrib += loss_term(pr, l, sbox[i2], sga[i2]);
            np++;
        }
    }

    const int lane = tid & 63, wv = tid >> 6;
    for (int off = 32; off; off >>= 1) {
        contrib += __shfl_down(contrib, off, 64);
        np      += __shfl_down(np, off, 64);
    }
    if (lane == 0) { rs[wv] = contrib; rn[wv] = np; }
    __syncthreads();  // kgrid + rs/rn visible

    // per-gt argmax within block: 4 readers per gt scan 32 entries each
    if (tid < 192) {
        int g = tid >> 2, qq = tid & 3;
        const uint4* row = (const uint4*)&kgrid[g * ROW + qq * 32];
        unsigned int m = 0u;
#pragma unroll
        for (int i = 0; i < 8; i++) {
            uint4 v = row[i];
            m = max(max(m, v.x), max(v.y, max(v.z, v.w)));
        }
        pmax[g][qq] = m;
    }
    __syncthreads();

    if (tid < G_) {
        unsigned int w = max(max(pmax[tid][0], pmax[tid][1]),
                             max(pmax[tid][2], pmax[tid][3]));
        int p = base + 1023 - (int)(w & 0x3FFu);
        p = min(p, P_ - 1);  // defensive; unreachable via tie-break
        float4 pr = ((const float4*)priors)[p];
        float hx = pr.z * 0.5f, hy = pr.w * 0.5f;
        float qx1 = pr.x - hx, qy1 = pr.y - hy, qx2 = pr.x + hx, qy2 = pr.y + hy;
        float pae = (qx2 - qx1) * (qy2 - qy1);
        float4 gb = sbox[tid];
        float ix1 = fmaxf(gb.x, qx1), iy1 = fmaxf(gb.y, qy1);
        float ix2 = fminf(gb.z, qx2), iy2 = fminf(gb.w, qy2);
        float iw = fmaxf(ix2 - ix1, 0.0f), ih = fmaxf(iy2 - iy1, 0.0f);
        float inter = iw * ih;
        // exact (bit-stable across blocks) IoU-form key for cross-block comparison
        float v = inter * frcp(sga[tid] + pae - inter);
        // layout [b][g][chunk]: tail kernel reads each (b,g)'s 24 keys contiguously
        bkey[((size_t)b * G_ + tid) * NCH + blockIdx.x] =
            ((unsigned long long)__float_as_uint(v) << 32) |
            (unsigned long long)(0xFFFFFFFFu - (unsigned)p);
    }

    if (tid == 0) {
        pl[b * NCH + blockIdx.x] = rs[0] + rs[1] + rs[2] + rs[3];
        pn[b * NCH + blockIdx.x] = rn[0] + rn[1] + rn[2] + rn[3];
    }
}

// ---------------- K2: bkey reduce + override corrections + final sum (one block) ------------
__global__ __launch_bounds__(1024) void fix_final_kernel(
    const float* __restrict__ pred_loc, const float* __restrict__ priors,
    const float* __restrict__ gt, const unsigned long long* __restrict__ bkey,
    const unsigned short* __restrict__ mrec,
    const float* __restrict__ pl, const unsigned int* __restrict__ pn,
    float* __restrict__ out) {
    const int tid = threadIdx.x;
    __shared__ int sp[B_ * G_];   // best prior per (b,g), 12 KB

    // phase 1: reduce 24 contiguous keys per (b,g) — 590 KB sequential
    for (int i = tid; i < B_ * G_; i += 1024) {
        const unsigned long long* row = bkey + (size_t)i * NCH;
        unsigned long long m = 0ull;
#pragma unroll
        for (int c = 0; c < NCH; c++) m = max(m, row[c]);
        sp[i] = (int)(0xFFFFFFFFu - (unsigned)(m & 0xFFFFFFFFull));
    }
    __syncthreads();

    // phase 2: override corrections
    float dl = 0.0f;
    unsigned int dn = 0;
    for (int i = tid; i < B_ * G_; i += 1024) {
        int b = i / G_, g = i - b * G_;
        int p = sp[i];
        // last-write-wins: g is alive iff no larger g' in the same image shares p
        bool alive = true;
        for (int d = g + 1; d < G_; d++)
            if (sp[b * G_ + d] == p) alive = false;
        if (alive) {
            unsigned int m = mrec[(size_t)b * PAD_P + p];
            int i1 = (int)(m & 63u), i2 = (int)((m >> 6) & 63u);
            bool pos0 = (m >> 12) & 1u;
            int ri = (g == i1) ? i2 : i1;   // override bi=g -> rep flips to i1 unless g==i1
            float4 pr = ((const float4*)priors)[p];
            float4 l  = ((const float4*)pred_loc)[(size_t)b * P_ + p];
            const float* qr = gt + ((size_t)b * G_ + ri) * 5;
            float4 gbr = make_float4(qr[0], qr[1], qr[2], qr[3]);
            float gar = (qr[2] - qr[0]) * (qr[3] - qr[1]);
            float cnew = loss_term(pr, l, gbr, gar);
            float cold = 0.0f;
            if (pos0) {
                const float* q2 = gt + ((size_t)b * G_ + i2) * 5;
                float4 gb2 = make_float4(q2[0], q2[1], q2[2], q2[3]);
                float ga2 = (q2[2] - q2[0]) * (q2[3] - q2[1]);
                cold = loss_term(pr, l, gb2, ga2);   // cancels match's default term
            } else {
                dn++;                                 // prior newly positive
            }
            dl += cnew - cold;
        }
    }

    // phase 3: fold per-block partials
    for (int i = tid; i < NBLK; i += 1024) { dl += pl[i]; dn += pn[i]; }

    for (int off = 32; off; off >>= 1) {
        dl += __shfl_down(dl, off, 64);
        dn += __shfl_down(dn, off, 64);
    }
    __shared__ float wd[16];
    __shared__ unsigned int wn[16];
    const int lane = tid & 63, wv = tid >> 6;
    if (lane == 0) { wd[wv] = dl; wn[wv] = dn; }
    __syncthreads();
    if (tid == 0) {
        double s = 0.0;
        unsigned int n = 0;
        for (int i = 0; i < 16; i++) { s += (double)wd[i]; n += wn[i]; }
        out[0] = (float)(s / (double)n);
    }
}

extern "C" void kernel_launch(void* const* d_in, const int* in_sizes, int n_in,
                              void* d_out, int out_size, void* d_ws, size_t ws_size,
                              hipStream_t stream) {
    const float* pred_loc = (const float*)d_in[0];  // [B,P,4]
    const float* priors   = (const float*)d_in[1];  // [P,4]
    const float* gt       = (const float*)d_in[2];  // [B,G,5]
    float* out = (float*)d_out;

    char* ws = (char*)d_ws;
    unsigned long long* bkey = (unsigned long long*)ws;                   // 589824 B
    unsigned short* mrec = (unsigned short*)(ws + 589824);                // 3145728 B
    float*        pl   = (float*)(ws + 3735552);                          // 6144 B
    unsigned int* pn   = (unsigned int*)(ws + 3741696);                   // 6144 B

    dim3 g1(NCH, B_);
    match_kernel<<<g1, 256, 0, stream>>>(pred_loc, priors, gt, bkey, mrec, pl, pn);

    fix_final_kernel<<<1, 1024, 0, stream>>>(pred_loc, priors, gt, bkey, mrec, pl, pn, out);
}

// Round 9
// 122.997 us; speedup vs baseline: 1.9365x; 1.1672x over previous
//
#include <hip/hip_runtime.h>
#include <math.h>

#define B_ 64
#define P_ 24564
#define G_ 48

// Workspace layout (total ~3.75 MB), everything fully overwritten every call (no memset):
//   [0]        unsigned long long bkey[B_][G_][NCH]   per-(b,g,chunk) best-prior keys
//   [589824]   unsigned short mrec[B_*PAD_P]          i1|i2<<6|pos<<12
//   [3735552]  float        pl[NBLK]                  per-block loss partials
//   [3741696]  unsigned int pn[NBLK]                  per-block npos partials
//   [3747840]  double       corrl[B_]                 per-image corrections
//   [3748352]  unsigned int corrn[B_]
constexpr int CH    = 1024;
constexpr int NCH   = 24;               // 24*1024 = 24576 >= P_
constexpr int PAD_P = NCH * CH;
constexpr int PPT   = 4;
constexpr int NBLK  = NCH * B_;         // 1536
constexpr int ROW   = 132;              // kgrid row in u32 (128 entries + pad)

__device__ __forceinline__ float frcp(float x) { return __builtin_amdgcn_rcpf(x); }

// Smooth-ln repulsion term; identical in match (default) and fix (correction) so terms cancel.
__device__ __forceinline__ float loss_term(float4 pr, float4 l, float4 gb, float ga) {
    float cx = pr.x + l.x * 0.1f * pr.z;
    float cy = pr.y + l.y * 0.1f * pr.w;
    float w  = pr.z * expf(l.z * 0.2f);
    float h  = pr.w * expf(l.w * 0.2f);
    float dx1 = cx - w * 0.5f, dy1 = cy - h * 0.5f;
    float dx2 = cx + w * 0.5f, dy2 = cy + h * 0.5f;
    float ix1 = fmaxf(gb.x, dx1), iy1 = fmaxf(gb.y, dy1);
    float ix2 = fminf(gb.z, dx2), iy2 = fminf(gb.w, dy2);
    float iw = fmaxf(ix2 - ix1, 0.0f), ih = fmaxf(iy2 - iy1, 0.0f);
    float iogv = (iw * ih) * frcp(ga + 1e-7f);
    float r = 0.0f;
    if (iogv < 0.95f) {
        if (iogv < 0.5f)
            r = -logf(1.0f - iogv + 1e-7f);
        else
            r = (iogv - 0.5f) * 2.0f + 0.69314718055994531f;  // -ln(0.5)
    }
    return r;
}

// ---------------- K1: fused — top-2 per prior, per-gt block argmax, default loss ------------
__global__ __launch_bounds__(256) void match_kernel(
    const float* __restrict__ pred_loc, const float* __restrict__ priors,
    const float* __restrict__ gt, unsigned long long* __restrict__ bkey,
    unsigned short* __restrict__ mrec, float* __restrict__ pl, unsigned int* __restrict__ pn) {
    const int b    = blockIdx.y;
    const int base = blockIdx.x * CH;
    const int tid  = threadIdx.x;

    __shared__ float4 sbox[G_];
    __shared__ float  sga[G_];
    __shared__ unsigned int kgrid[G_ * ROW];   // pair-reduced per-gt candidate keys
    __shared__ unsigned int pmax[G_][4];
    __shared__ float rs[4];
    __shared__ unsigned int rn[4];

    if (tid < G_) {
        const float* q = gt + ((size_t)b * G_ + tid) * 5;
        float x1 = q[0], y1 = q[1], x2 = q[2], y2 = q[3];
        sbox[tid] = make_float4(x1, y1, x2, y2);
        sga[tid]  = (x2 - x1) * (y2 - y1);
    }
    __syncthreads();

    float px1[PPT], py1[PPT], px2[PPT], py2[PPT], pa[PPT];
    unsigned int tb[PPT];  // 1023 - local_p (per-gt tie-break: lower p wins)
#pragma unroll
    for (int j = 0; j < PPT; j++) {
        int lp = tid + 256 * j;
        int pc = min(base + lp, P_ - 1);  // clamped OOB dup loses tie-break to the real one
        float4 pr = ((const float4*)priors)[pc];
        float hx = pr.z * 0.5f, hy = pr.w * 0.5f;
        px1[j] = pr.x - hx; py1[j] = pr.y - hy;
        px2[j] = pr.x + hx; py2[j] = pr.y + hy;
        pa[j] = (px2[j] - px1[j]) * (py2[j] - py1[j]);
        tb[j] = (unsigned)(1023 - lp);
    }

    unsigned int k1[PPT], k2[PPT];  // packed top-2 of r=inter/(ga+pa): (r&~0x3F)|(63-g)
#pragma unroll
    for (int j = 0; j < PPT; j++) { k1[j] = 0u; k2[j] = 0u; }

#pragma unroll 8
    for (int g = 0; g < G_; g++) {
        float4 gb = sbox[g];
        float  ga = sga[g];
        unsigned int gmax = 0u;
#pragma unroll
        for (int j = 0; j < PPT; j++) {
            float ix1 = fmaxf(gb.x, px1[j]), iy1 = fmaxf(gb.y, py1[j]);
            float ix2 = fminf(gb.z, px2[j]), iy2 = fminf(gb.w, py2[j]);
            float iw = fmaxf(ix2 - ix1, 0.0f), ih = fmaxf(iy2 - iy1, 0.0f);
            float inter = iw * ih;
            // r = inter/(ga+pa) is a monotone transform of IoU=inter/(ga+pa-inter)
            float r = inter * frcp(ga + pa[j]);
            unsigned int vb = __float_as_uint(r);
            unsigned int pk = (vb & 0xFFFFFFC0u) | (unsigned)(63 - g);
            k2[j] = max(k2[j], min(k1[j], pk));
            k1[j] = max(k1[j], pk);
            unsigned int gk = (vb & 0xFFFFFC00u) | tb[j];
            gmax = max(gmax, gk);
        }
        // pair-reduce across adjacent lanes, even lanes store -> 128-entry rows
        unsigned int o = __shfl_down(gmax, 1, 64);
        if ((tid & 1) == 0) kgrid[g * ROW + (tid >> 1)] = max(gmax, o);
    }

    // per-prior epilogue: default contribution assumes NO override (bi=i1 -> rep=i2)
    float contrib = 0.0f;
    unsigned int np = 0;
#pragma unroll
    for (int j = 0; j < PPT; j++) {
        int p = base + tid + 256 * j;
        unsigned int i1 = 63u - (k1[j] & 63u);
        unsigned int i2 = 63u - (k2[j] & 63u);
        // r >= 1/3  <=>  IoU >= 0.5 ; truncated-key threshold (bits(1/3f) & ~0x3F)
        unsigned int pos = (k1[j] >= 0x3EAAAA80u) ? 1u : 0u;
        mrec[(size_t)b * PAD_P + base + tid + 256 * j] =
            (unsigned short)(i1 | (i2 << 6) | (pos << 12));
        if (p < P_ && pos) {
            float4 pr = ((const float4*)priors)[p];               // L1-hot reload
            float4 l  = ((const float4*)pred_loc)[(size_t)b * P_ + p];
            contrib += loss_term(pr, l, sbox[i2], sga[i2]);
            np++;
        }
    }

    const int lane = tid & 63, wv = tid >> 6;
    for (int off = 32; off; off >>= 1) {
        contrib += __shfl_down(contrib, off, 64);
        np      += __shfl_down(np, off, 64);
    }
    if (lane == 0) { rs[wv] = contrib; rn[wv] = np; }
    __syncthreads();  // kgrid + rs/rn visible

    // per-gt argmax within block: 4 readers per gt scan 32 entries each
    if (tid < 192) {
        int g = tid >> 2, qq = tid & 3;
        const uint4* row = (const uint4*)&kgrid[g * ROW + qq * 32];
        unsigned int m = 0u;
#pragma unroll
        for (int i = 0; i < 8; i++) {
            uint4 v = row[i];
            m = max(max(m, v.x), max(v.y, max(v.z, v.w)));
        }
        pmax[g][qq] = m;
    }
    __syncthreads();

    if (tid < G_) {
        unsigned int w = max(max(pmax[tid][0], pmax[tid][1]),
                             max(pmax[tid][2], pmax[tid][3]));
        int p = base + 1023 - (int)(w & 0x3FFu);
        p = min(p, P_ - 1);  // defensive; unreachable via tie-break
        float4 pr = ((const float4*)priors)[p];
        float hx = pr.z * 0.5f, hy = pr.w * 0.5f;
        float qx1 = pr.x - hx, qy1 = pr.y - hy, qx2 = pr.x + hx, qy2 = pr.y + hy;
        float pae = (qx2 - qx1) * (qy2 - qy1);
        float4 gb = sbox[tid];
        float ix1 = fmaxf(gb.x, qx1), iy1 = fmaxf(gb.y, qy1);
        float ix2 = fminf(gb.z, qx2), iy2 = fminf(gb.w, qy2);
        float iw = fmaxf(ix2 - ix1, 0.0f), ih = fmaxf(iy2 - iy1, 0.0f);
        float inter = iw * ih;
        // exact (bit-stable across blocks) IoU-form key for cross-block comparison
        float v = inter * frcp(sga[tid] + pae - inter);
        // layout [b][g][chunk]: fix kernel reads each (b,g)'s 24 keys contiguously
        bkey[((size_t)b * G_ + tid) * NCH + blockIdx.x] =
            ((unsigned long long)__float_as_uint(v) << 32) |
            (unsigned long long)(0xFFFFFFFFu - (unsigned)p);
    }

    if (tid == 0) {
        pl[b * NCH + blockIdx.x] = rs[0] + rs[1] + rs[2] + rs[3];
        pn[b * NCH + blockIdx.x] = rn[0] + rn[1] + rn[2] + rn[3];
    }
}

// ---------------- K2: per-image bkey reduce + override corrections (64 blocks) --------------
__global__ __launch_bounds__(64) void fix_kernel(
    const float* __restrict__ pred_loc, const float* __restrict__ priors,
    const float* __restrict__ gt, const unsigned long long* __restrict__ bkey,
    const unsigned short* __restrict__ mrec,
    double* __restrict__ corrl, unsigned int* __restrict__ corrn) {
    const int b = blockIdx.x, g = threadIdx.x;
    __shared__ int sp[G_];
    int p = -1;
    if (g < G_) {
        const unsigned long long* row = bkey + ((size_t)b * G_ + g) * NCH;
        unsigned long long m = 0ull;
#pragma unroll
        for (int c = 0; c < NCH; c++) m = max(m, row[c]);
        p = (int)(0xFFFFFFFFu - (unsigned)(m & 0xFFFFFFFFull));
        sp[g] = p;
    }
    __syncthreads();

    double delta = 0.0;
    unsigned int dn = 0;
    if (g < G_) {
        // last-write-wins: g is alive iff no larger g' shares the same best prior
        bool alive = true;
        for (int d = g + 1; d < G_; d++)
            if (sp[d] == p) alive = false;
        if (alive) {
            unsigned int m = mrec[(size_t)b * PAD_P + p];
            int i1 = (int)(m & 63u), i2 = (int)((m >> 6) & 63u);
            bool pos0 = (m >> 12) & 1u;
            int ri = (g == i1) ? i2 : i1;   // override bi=g -> rep flips to i1 unless g==i1
            float4 pr = ((const float4*)priors)[p];
            float4 l  = ((const float4*)pred_loc)[(size_t)b * P_ + p];
            const float* qr = gt + ((size_t)b * G_ + ri) * 5;
            float4 gbr = make_float4(qr[0], qr[1], qr[2], qr[3]);
            float gar = (qr[2] - qr[0]) * (qr[3] - qr[1]);
            float cnew = loss_term(pr, l, gbr, gar);
            float cold = 0.0f;
            if (pos0) {
                const float* q2 = gt + ((size_t)b * G_ + i2) * 5;
                float4 gb2 = make_float4(q2[0], q2[1], q2[2], q2[3]);
                float ga2 = (q2[2] - q2[0]) * (q2[3] - q2[1]);
                cold = loss_term(pr, l, gb2, ga2);   // cancels match's default term
            } else {
                dn = 1;                               // prior newly positive
            }
            delta = (double)cnew - (double)cold;
        }
    }
    for (int off = 32; off; off >>= 1) {
        delta += __shfl_down(delta, off, 64);
        dn    += __shfl_down(dn, off, 64);
    }
    if (g == 0) { corrl[b] = delta; corrn[b] = dn; }
}

// ---------------- K3: final reduction --------------------------------------------------------
__global__ __launch_bounds__(256) void final_kernel(
    const float* __restrict__ pl, const unsigned int* __restrict__ pn,
    const double* __restrict__ corrl, const unsigned int* __restrict__ corrn,
    float* __restrict__ out) {
    const int tid = threadIdx.x;
    double acc = 0.0;
    unsigned int n = 0;
    for (int i = tid; i < NBLK; i += 256) { acc += (double)pl[i]; n += pn[i]; }
    if (tid < B_) { acc += corrl[tid]; n += corrn[tid]; }
    for (int off = 32; off; off >>= 1) {
        acc += __shfl_down(acc, off, 64);
        n   += __shfl_down(n, off, 64);
    }
    __shared__ double ds[4];
    __shared__ unsigned int dns[4];
    const int lane = tid & 63, wv = tid >> 6;
    if (lane == 0) { ds[wv] = acc; dns[wv] = n; }
    __syncthreads();
    if (tid == 0) {
        double s = ds[0] + ds[1] + ds[2] + ds[3];
        unsigned int nn = dns[0] + dns[1] + dns[2] + dns[3];
        out[0] = (float)(s / (double)nn);
    }
}

extern "C" void kernel_launch(void* const* d_in, const int* in_sizes, int n_in,
                              void* d_out, int out_size, void* d_ws, size_t ws_size,
                              hipStream_t stream) {
    const float* pred_loc = (const float*)d_in[0];  // [B,P,4]
    const float* priors   = (const float*)d_in[1];  // [P,4]
    const float* gt       = (const float*)d_in[2];  // [B,G,5]
    float* out = (float*)d_out;

    char* ws = (char*)d_ws;
    unsigned long long* bkey = (unsigned long long*)ws;                   // 589824 B
    unsigned short* mrec = (unsigned short*)(ws + 589824);                // 3145728 B
    float*        pl    = (float*)(ws + 3735552);                         // 6144 B
    unsigned int* pn    = (unsigned int*)(ws + 3741696);                  // 6144 B
    double*       corrl = (double*)(ws + 3747840);                        // 512 B
    unsigned int* corrn = (unsigned int*)(ws + 3748352);                  // 256 B

    dim3 g1(NCH, B_);
    match_kernel<<<g1, 256, 0, stream>>>(pred_loc, priors, gt, bkey, mrec, pl, pn);

    fix_kernel<<<B_, 64, 0, stream>>>(pred_loc, priors, gt, bkey, mrec, corrl, corrn);

    final_kernel<<<1, 256, 0, stream>>>(pl, pn, corrl, corrn, out);
}